// Round 5
// baseline (553.692 us; speedup 1.0000x reference)
//
#include <hip/hip_runtime.h>
#include <math.h>

#define V 50257
#define B 64
#define HD 1024
#define LSRC 128
#define NBLK 786        // k_gemm blocks: 786*64 = 50304 >= V
#define NP (NBLK * 4)   // per-wave LSE partials per batch row

typedef float v4f __attribute__((ext_vector_type(4)));
typedef __bf16 v8bf __attribute__((ext_vector_type(8)));
typedef unsigned short v8us __attribute__((ext_vector_type(8)));

__device__ inline unsigned short bf_rne(float x) {
    unsigned int u = __float_as_uint(x);
    return (unsigned short)((u + 0x7fffu + ((u >> 16) & 1u)) >> 16);
}
__device__ inline unsigned int pk2_rne(float x, float y) {
    return (unsigned int)bf_rne(x) | ((unsigned int)bf_rne(y) << 16);
}

// ---------- 1. gather emb + h0 -> catB (b-major, [emb|h0]); actC emb half ----------
__global__ void k_prep(const int* __restrict__ idx, const float* __restrict__ hidden,
                       const float* __restrict__ emb, unsigned short* __restrict__ catB,
                       unsigned short* __restrict__ actC) {
    int i = blockIdx.x * 256 + threadIdx.x;   // 64*2048
    int b = i >> 11, k = i & 2047;
    unsigned short v;
    if (k < 1024) {
        v = bf_rne(emb[(size_t)idx[b] * 1024 + k]);
        actC[b * 2048 + k] = v;
    } else {
        v = bf_rne(hidden[b * 1024 + (k - 1024)]);
    }
    catB[b * 2048 + k] = v;
}

// ---------- split-K MFMA GEMM core: P[ks][b][M] = W[rows,:k-chunk] . act ----------
__device__ __forceinline__ void mm_core(const float* __restrict__ W,
                                        const unsigned short* __restrict__ act, int as_,
                                        float* __restrict__ P, int M, int K, int Kc,
                                        int mx, int ks, int tid) {
    int wave = tid >> 6, lane = tid & 63;
    int quad = lane >> 4, r16 = lane & 15;
    int row0 = mx * 64 + wave * 16;
    int kbase = ks * Kc;
    const float* wr = W + (size_t)(row0 + r16) * K + kbase + quad * 8;
    const unsigned short* ab = act + kbase + quad * 8;
    v4f acc[4] = {};
    for (int kk = 0; kk < Kc; kk += 32) {
        float4 p0 = *(const float4*)(wr + kk);
        float4 p1 = *(const float4*)(wr + kk + 4);
        union { unsigned int u[4]; v8us v; } A;
        A.u[0] = pk2_rne(p0.x, p0.y); A.u[1] = pk2_rne(p0.z, p0.w);
        A.u[2] = pk2_rne(p1.x, p1.y); A.u[3] = pk2_rne(p1.z, p1.w);
        v8bf af = __builtin_bit_cast(v8bf, A.v);
        #pragma unroll
        for (int nt = 0; nt < 4; ++nt) {
            v8us bu = *(const v8us*)(ab + (size_t)(nt * 16 + r16) * as_ + kk);
            v8bf bf = __builtin_bit_cast(v8bf, bu);
            acc[nt] = __builtin_amdgcn_mfma_f32_16x16x32_bf16(af, bf, acc[nt], 0, 0, 0);
        }
    }
    float* po = P + (size_t)ks * 64 * M;
    #pragma unroll
    for (int nt = 0; nt < 4; ++nt) {
        int b = nt * 16 + r16;
        float4 val = make_float4(acc[nt][0], acc[nt][1], acc[nt][2], acc[nt][3]);
        *(float4*)(po + (size_t)b * M + row0 + quad * 4) = val;
    }
}

__global__ __launch_bounds__(256) void k_mm(const float* __restrict__ W,
                                            const unsigned short* __restrict__ act,
                                            float* __restrict__ P, int M, int K, int Kc,
                                            int as_) {
    mm_core(W, act, as_, P, M, K, Kc, blockIdx.x, blockIdx.y, threadIdx.x);
}

// fused: comb GEMM (bx<16) + w_hh GEMM (bx>=16)
__global__ __launch_bounds__(256) void k_mm2(const float* __restrict__ Wc,
                                             const unsigned short* __restrict__ actC,
                                             float* __restrict__ Pc,
                                             const float* __restrict__ Wh,
                                             const unsigned short* __restrict__ h0B,
                                             float* __restrict__ Ph) {
    int bx = blockIdx.x;
    if (bx < 16) mm_core(Wc, actC, 2048, Pc, 1024, 2048, 512, bx, blockIdx.y, threadIdx.x);
    else         mm_core(Wh, h0B, 2048, Ph, 3072, 1024, 256, bx - 16, blockIdx.y, threadIdx.x);
}

// ---------- 3. softmax(attn partials) + context -> actC[b][1024+e]; out2 ----------
__global__ void k_ctxs(const float* __restrict__ Pa, const float* __restrict__ attn_b,
                       const float* __restrict__ enc, unsigned short* __restrict__ actC,
                       float* __restrict__ out2) {
    __shared__ float a_sh[128];
    __shared__ float red[8];
    int b = blockIdx.y, tid = threadIdx.x;
    int lane = tid & 63, wave = tid >> 6;
    float x = -1e30f;
    if (tid < 128) {
        x = attn_b[tid];
        #pragma unroll
        for (int ks = 0; ks < 4; ++ks) x += Pa[(ks * 64 + b) * 128 + tid];
    }
    float m = x;
    #pragma unroll
    for (int off = 32; off; off >>= 1) m = fmaxf(m, __shfl_xor(m, off));
    if (lane == 0) red[wave] = m;
    __syncthreads();
    m = fmaxf(fmaxf(red[0], red[1]), fmaxf(red[2], red[3]));
    float e = (tid < 128) ? __expf(x - m) : 0.f;
    float ssum = e;
    #pragma unroll
    for (int off = 32; off; off >>= 1) ssum += __shfl_xor(ssum, off);
    if (lane == 0) red[4 + wave] = ssum;
    __syncthreads();
    float stot = red[4] + red[5] + red[6] + red[7];
    if (tid < 128) {
        float w = e / stot;
        a_sh[tid] = w;
        if (blockIdx.x == 0) out2[b * 128 + tid] = w;
    }
    __syncthreads();
    int e0 = blockIdx.x * 256 + tid;
    float acc0 = 0.f, acc1 = 0.f, acc2 = 0.f, acc3 = 0.f;
    #pragma unroll
    for (int l = 0; l < 128; l += 4) {
        acc0 += a_sh[l]     * enc[((size_t)((l + 0) * 64) + b) * 1024 + e0];
        acc1 += a_sh[l + 1] * enc[((size_t)((l + 1) * 64) + b) * 1024 + e0];
        acc2 += a_sh[l + 2] * enc[((size_t)((l + 2) * 64) + b) * 1024 + e0];
        acc3 += a_sh[l + 3] * enc[((size_t)((l + 3) * 64) + b) * 1024 + e0];
    }
    actC[b * 2048 + 1024 + e0] = bf_rne((acc0 + acc1) + (acc2 + acc3));
}

// ---------- 5. reduce comb partials + bias + relu -> xB bf16 ----------
__global__ void k_redc(const float* __restrict__ Pc, const float* __restrict__ comb_b,
                       unsigned short* __restrict__ xB) {
    int i = blockIdx.x * 256 + threadIdx.x;  // 64*1024
    int b = i >> 10, k = i & 1023;
    float s = comb_b[k];
    #pragma unroll
    for (int ss = 0; ss < 4; ++ss) s += Pc[((size_t)ss * 64 + b) * 1024 + k];
    s = fmaxf(s, 0.f);
    xB[b * 1024 + k] = bf_rne(s);
}

// ---------- 6. GRU gates (folds split-K reduction of gi/gh) ----------
__global__ void k_gates(const float* __restrict__ Pi, const float* __restrict__ Ph,
                        const float* __restrict__ b_ih, const float* __restrict__ b_hh,
                        const float* __restrict__ hidden, float* __restrict__ out1,
                        unsigned short* __restrict__ hbf) {
    int i = blockIdx.x * 256 + threadIdx.x;  // 64*1024
    int b = i >> 10, u = i & 1023;
    float ir = b_ih[u], iz = b_ih[1024 + u], in_ = b_ih[2048 + u];
    float hr = b_hh[u], hz = b_hh[1024 + u], hn = b_hh[2048 + u];
    #pragma unroll
    for (int s = 0; s < 4; ++s) {
        const float* pi = Pi + ((size_t)s * 64 + b) * 3072;
        const float* ph = Ph + ((size_t)s * 64 + b) * 3072;
        ir += pi[u]; iz += pi[1024 + u]; in_ += pi[2048 + u];
        hr += ph[u]; hz += ph[1024 + u]; hn += ph[2048 + u];
    }
    float r = 1.f / (1.f + __expf(-(ir + hr)));
    float z = 1.f / (1.f + __expf(-(iz + hz)));
    float n = tanhf(in_ + r * hn);
    float h0 = hidden[b * 1024 + u];
    float h = (1.f - z) * n + z * h0;
    out1[b * 1024 + u] = h;
    hbf[b * 1024 + u] = bf_rne(h);
}

// ---------- 7. logits + bias + per-wave online LSE partials (LDS-staged A) ----------
// A tile: 64 rows x 128 K f32, double-buffered = 64 KB LDS (2 blocks/CU).
// Staging: each thread loads 128 B contiguous -> wave streams 8 KB contiguous (DRAM-friendly).
__global__ __launch_bounds__(256, 2) void k_gemm(const float* __restrict__ Wt,
                                                 const unsigned short* __restrict__ hbf,
                                                 const float* __restrict__ out_b,
                                                 float* __restrict__ out0,
                                                 float* __restrict__ m_part,
                                                 float* __restrict__ s_part) {
    __shared__ float Abuf[2][64 * 128];   // 2 x 32 KB
    int tid = threadIdx.x;
    int wave = tid >> 6, lane = tid & 63;
    int quad = lane >> 4, r16 = lane & 15;
    int row0 = blockIdx.x * 64;
    int v0 = row0 + wave * 16;

    // staging addresses: thread covers floats [tid*32, tid*32+32) of the 8192-float tile
    int srow = tid >> 2;                         // 0..63
    int scol = (tid & 3) * 32;                   // 0,32,64,96
    int grow = min(row0 + srow, V - 1);          // clamp tail rows
    const float* gsrc = Wt + (size_t)grow * 1024 + scol;
    float* lflat = &Abuf[0][0];                  // flat store: offset tid*32 + j*4

    float4 st[8];
    // prologue: load tile 0
    #pragma unroll
    for (int j = 0; j < 8; ++j) st[j] = *(const float4*)(gsrc + j * 4);
    #pragma unroll
    for (int j = 0; j < 8; ++j) *(float4*)(lflat + tid * 32 + j * 4) = st[j];
    __syncthreads();

    const unsigned short* bq = hbf + (size_t)r16 * 1024 + quad * 8;
    v4f acc[4] = {};
    for (int t = 0; t < 8; ++t) {
        if (t + 1 < 8) {
            const float* gs = gsrc + (t + 1) * 128;
            #pragma unroll
            for (int j = 0; j < 8; ++j) st[j] = *(const float4*)(gs + j * 4);
        }
        const float* ar = &Abuf[t & 1][(wave * 16 + r16) * 128 + quad * 8];
        #pragma unroll
        for (int kk = 0; kk < 128; kk += 32) {
            float4 p0 = *(const float4*)(ar + kk);
            float4 p1 = *(const float4*)(ar + kk + 4);
            union { unsigned int u[4]; v8us v; } A;
            A.u[0] = pk2_rne(p0.x, p0.y); A.u[1] = pk2_rne(p0.z, p0.w);
            A.u[2] = pk2_rne(p1.x, p1.y); A.u[3] = pk2_rne(p1.z, p1.w);
            v8bf af = __builtin_bit_cast(v8bf, A.v);
            int ko = t * 128 + kk;
            #pragma unroll
            for (int nt = 0; nt < 4; ++nt) {
                v8us bu = *(const v8us*)(bq + nt * 16384 + ko);
                v8bf bf = __builtin_bit_cast(v8bf, bu);
                acc[nt] = __builtin_amdgcn_mfma_f32_16x16x32_bf16(af, bf, acc[nt], 0, 0, 0);
            }
        }
        if (t + 1 < 8) {
            float* lf = &Abuf[(t + 1) & 1][0];
            #pragma unroll
            for (int j = 0; j < 8; ++j) *(float4*)(lf + tid * 32 + j * 4) = st[j];
        }
        __syncthreads();
    }

    // epilogue: bias + store + per-wave LSE partials
    #pragma unroll
    for (int nt = 0; nt < 4; ++nt) {
        int b = nt * 16 + r16;
        float lm = -1e30f, lsum = 0.f;
        #pragma unroll
        for (int r = 0; r < 4; ++r) {
            int v = v0 + quad * 4 + r;
            if (v < V) {
                float x = acc[nt][r] + out_b[v];
                out0[(size_t)b * V + v] = x;
                float nm = fmaxf(lm, x);
                lsum = lsum * __expf(lm - nm) + __expf(x - nm);
                lm = nm;
            }
        }
        #pragma unroll
        for (int off = 16; off <= 32; off <<= 1) {
            float om = __shfl_xor(lm, off), os = __shfl_xor(lsum, off);
            float nm = fmaxf(lm, om);
            lsum = lsum * __expf(lm - nm) + os * __expf(om - nm);
            lm = nm;
        }
        if (quad == 0) {
            m_part[(size_t)b * NP + blockIdx.x * 4 + wave] = lm;
            s_part[(size_t)b * NP + blockIdx.x * 4 + wave] = lsum;
        }
    }
}

// ---------- 8. combine per-wave partials -> lse[b] ----------
__global__ void k_comb(const float* __restrict__ m_part, const float* __restrict__ s_part,
                       float* __restrict__ lse) {
    __shared__ float sm[4], ss[4];
    int b = blockIdx.x, tid = threadIdx.x;
    int lane = tid & 63, wave = tid >> 6;
    float m = -1e30f, s = 0.f;
    for (int i = tid; i < NP; i += 256) {
        float om = m_part[(size_t)b * NP + i], os = s_part[(size_t)b * NP + i];
        float nm = fmaxf(m, om);
        s = s * __expf(m - nm) + os * __expf(om - nm);
        m = nm;
    }
    #pragma unroll
    for (int off = 32; off; off >>= 1) {
        float om = __shfl_xor(m, off), os = __shfl_xor(s, off);
        float nm = fmaxf(m, om);
        s = s * __expf(m - nm) + os * __expf(om - nm);
        m = nm;
    }
    if (lane == 0) { sm[wave] = m; ss[wave] = s; }
    __syncthreads();
    if (tid == 0) {
        float M = sm[0], S = ss[0];
        #pragma unroll
        for (int w = 1; w < 4; ++w) {
            float nm = fmaxf(M, sm[w]);
            S = S * __expf(M - nm) + ss[w] * __expf(sm[w] - nm);
            M = nm;
        }
        lse[b] = M + __logf(S);
    }
}

// ---------- 9. subtract lse in place ----------
__global__ void k_final(float* __restrict__ out0, const float* __restrict__ lse) {
    int b = blockIdx.y;
    float l = lse[b];
    int base = blockIdx.x * 2048 + threadIdx.x;
    #pragma unroll
    for (int j = 0; j < 8; ++j) {
        int v = base + j * 256;
        if (v < V) out0[(size_t)b * V + v] -= l;
    }
}

extern "C" void kernel_launch(void* const* d_in, const int* in_sizes, int n_in,
                              void* d_out, int out_size, void* d_ws, size_t ws_size,
                              hipStream_t stream) {
    const int*   input_tensor = (const int*)d_in[0];
    const float* hidden  = (const float*)d_in[1];
    const float* enc     = (const float*)d_in[2];
    const float* emb     = (const float*)d_in[4];
    const float* attn_w  = (const float*)d_in[5];
    const float* attn_b  = (const float*)d_in[6];
    const float* comb_w  = (const float*)d_in[7];
    const float* comb_b  = (const float*)d_in[8];
    const float* w_ih    = (const float*)d_in[9];
    const float* w_hh    = (const float*)d_in[10];
    const float* b_ih    = (const float*)d_in[11];
    const float* b_hh    = (const float*)d_in[12];
    const float* out_w   = (const float*)d_in[13];
    const float* out_b   = (const float*)d_in[14];

    float* out0 = (float*)d_out;                 // [64][50257]
    float* out1 = out0 + (size_t)B * V;          // [64][1024]
    float* out2 = out1 + B * HD;                 // [64][128]

    // ws layout (float offsets); 64*2048 bf16 = 65536 floats
    float* ws = (float*)d_ws;
    float* Pa     = ws;                      // [0, 32768)
    float* Pc     = ws + 32768;              // [32768, 294912)
    float* lse    = ws + 294912;             // [294912, 294976)
    float* m_part = ws + 294976;             // [294976, 496192)   64*3144
    float* s_part = ws + 496192;             // [496192, 697408)   64*3144
    unsigned short* catB = (unsigned short*)(ws + 697408);  // 64*2048 bf16 (65536 f)
    unsigned short* actC = (unsigned short*)(ws + 762944);  // 64*2048 bf16 (65536 f)
    unsigned short* xB   = (unsigned short*)(ws + 828480);  // 64*1024 bf16 (16384 f)
    unsigned short* hbf  = (unsigned short*)(ws + 844864);  // 64*1024 bf16 (16384 f)

    // gi/gh split-K partials parked in the not-yet-written logits region of d_out
    float* Pi = out0;                      // 4*64*3072 f
    float* Ph = out0 + 4 * 64 * 3072;      // 4*64*3072 f

    k_prep<<<512, 256, 0, stream>>>(input_tensor, hidden, emb, catB, actC);
    k_mm<<<dim3(2, 4), 256, 0, stream>>>(attn_w, catB, Pa, 128, 2048, 512, 2048);
    k_ctxs<<<dim3(4, 64), 256, 0, stream>>>(Pa, attn_b, enc, actC, out2);
    k_mm2<<<dim3(64, 4), 256, 0, stream>>>(comb_w, actC, Pc, w_hh, catB + 1024, Ph);
    k_redc<<<256, 256, 0, stream>>>(Pc, comb_b, xB);
    k_mm<<<dim3(48, 4), 256, 0, stream>>>(w_ih, xB, Pi, 3072, 1024, 256, 1024);
    k_gates<<<256, 256, 0, stream>>>(Pi, Ph, b_ih, b_hh, hidden, out1, hbf);
    k_gemm<<<NBLK, 256, 0, stream>>>(out_w, hbf, out_b, out0, m_part, s_part);
    k_comb<<<64, 256, 0, stream>>>(m_part, s_part, lse);
    k_final<<<dim3(25, 64), 256, 0, stream>>>(out0, lse);
}